// Round 12
// baseline (509.152 us; speedup 1.0000x reference)
//
#include <hip/hip_runtime.h>
#include <cstddef>

#define T_SEQ 11
#define STEPS 80
#define SRC (-1.44269504f)
#define SNC ( 2.88539008f)

typedef _Float16 f16;
typedef _Float16 f16x4 __attribute__((ext_vector_type(4)));
typedef _Float16 f16x8 __attribute__((ext_vector_type(8)));
typedef float    f32x4 __attribute__((ext_vector_type(4)));

// ---- LDS layout (in halves unless noted) -------------------------------
// Each W set: 192 rows (R,Z,N gate blocks of 64 j) x 64 k, XOR-swizzled.
#define W0H   0        // l0 h-side weights (Whh0)
#define W1H   12288    // l1 h-side (Whh1)
#define W1X   24576    // l1 x-side (Wih1)
#define W0X   36864    // decoder l0 x-side (composed Wih0*fcW)
#define WPADO 49152    // 192x32 padded Wih0 (encoder l0 / decoder step0 x-side)
#define HB    55296    // 8 waves x (h0:1024 + h1:1024)
#define BIASH 71680    // f32 region starts here: 12 arrays x 64 floats
#define LDS_BYTES (71680*2 + 768*4)   // 146432 B

__device__ __forceinline__ f32x4 mfma16(f16x8 a, f16x8 b, f32x4 c) {
    return __builtin_amdgcn_mfma_f32_16x16x32_f16(a, b, c, 0, 0, 0);
}

// ---- staging -----------------------------------------------------------
__device__ __forceinline__ void stage_w(f16* lds, int dst, const float* __restrict__ W, int tid) {
    for (int c = tid; c < 1536; c += 512) {
        const int row = c >> 3, kc = c & 7;
        const float sc = (row < 128) ? SRC : SNC;
        const float* p = W + row * 64 + kc * 8;
        f16x8 v;
        #pragma unroll
        for (int i = 0; i < 8; ++i) v[i] = (f16)(sc * p[i]);
        *(f16x8*)(lds + dst + row * 64 + ((kc ^ (row & 7)) << 3)) = v;
    }
}
__device__ __forceinline__ void stage_comp(f16* lds, int dst, const float* __restrict__ Wih0,
                                           const float* __restrict__ fcW, int tid) {
    for (int c = tid; c < 1536; c += 512) {
        const int row = c >> 3, kc = c & 7;
        const float sc = (row < 128) ? SRC : SNC;
        const float a = Wih0[row * 2], b = Wih0[row * 2 + 1];
        f16x8 v;
        #pragma unroll
        for (int i = 0; i < 8; ++i)
            v[i] = (f16)(sc * (a * fcW[kc * 8 + i] + b * fcW[64 + kc * 8 + i]));
        *(f16x8*)(lds + dst + row * 64 + ((kc ^ (row & 7)) << 3)) = v;
    }
}
__device__ __forceinline__ void stage_pad(f16* lds, const float* __restrict__ Wih0, int tid) {
    for (int c = tid; c < 768; c += 512) {
        const int row = c >> 2, kc = c & 3;
        const float sc = (row < 128) ? SRC : SNC;
        f16x8 v;
        #pragma unroll
        for (int i = 0; i < 8; ++i) v[i] = (f16)0.f;
        if (kc == 0) { v[0] = (f16)(sc * Wih0[row * 2]); v[1] = (f16)(sc * Wih0[row * 2 + 1]); }
        *(f16x8*)(lds + WPADO + row * 32 + ((kc ^ (row & 3)) << 3)) = v;
    }
}
__device__ __forceinline__ void stage_bias(float* bb, int base, const float* __restrict__ bih,
                                           const float* __restrict__ bhh, int tid) {
    for (int t = tid; t < 256; t += 512) {
        const int a = t >> 6, j = t & 63;
        float v;
        if (a == 0)      v = SRC * (bih[j] + bhh[j]);
        else if (a == 1) v = SRC * (bih[64 + j] + bhh[64 + j]);
        else if (a == 2) v = SNC * bih[128 + j];
        else             v = SNC * bhh[128 + j];
        bb[(base + a) * 64 + j] = v;
    }
}
__device__ __forceinline__ void stage_bias_fold(float* bb, int base, const float* __restrict__ bih,
    const float* __restrict__ bhh, const float* __restrict__ Wih0, const float* __restrict__ fcb, int tid) {
    const float f0 = fcb[0], f1 = fcb[1];
    for (int t = tid; t < 256; t += 512) {
        const int a = t >> 6, j = t & 63;
        float v;
        if (a == 0)      { const int r = j;       v = SRC * (bih[r] + bhh[r] + Wih0[r*2]*f0 + Wih0[r*2+1]*f1); }
        else if (a == 1) { const int r = 64 + j;  v = SRC * (bih[r] + bhh[r] + Wih0[r*2]*f0 + Wih0[r*2+1]*f1); }
        else if (a == 2) { const int r = 128 + j; v = SNC * (bih[r] + Wih0[r*2]*f0 + Wih0[r*2+1]*f1); }
        else             v = SNC * bhh[128 + j];
        bb[(base + a) * 64 + j] = v;
    }
}

struct Lane {
    int col, quad, c7, colr, x0, x1;
    int wo[4];
};

// One GRU cell. Wave-private: D[j (4 m-tiles)][row=col (1 n-tile)].
// Weights from shared LDS (A-frags), h from this wave's private LDS region,
// in-place update (all h reads precede all writes in program order; same-wave
// lgkmcnt ordering makes this safe without any barrier).
// PADX: x-side is a single K=32 MFMA vs WPADO with caller-built B-frag xpb.
template<bool PADX>
__device__ __forceinline__ void cell_(f16* lds, int awh, int awx, int hxoff, int hhoff,
                                      int barr, const Lane& L, f16x4 (&ho)[4], f16x8 xpb)
{
    const float* bb = (const float*)(lds + BIASH);
    f16x8 xb0, xb1;
    if constexpr (!PADX) {
        xb0 = *(const f16x8*)(lds + hxoff + L.colr + L.x0);
        xb1 = *(const f16x8*)(lds + hxoff + L.colr + L.x1);
    }
    f16x8 hb0 = *(const f16x8*)(lds + hhoff + L.colr + L.x0);
    f16x8 hb1 = *(const f16x8*)(lds + hhoff + L.colr + L.x1);
    #pragma unroll
    for (int mtj = 0; mtj < 4; ++mtj) {
        const int bj = mtj * 16 + L.quad * 4;
        f32x4 bR  = *(const f32x4*)(bb + (barr + 0) * 64 + bj);
        f32x4 bZ  = *(const f32x4*)(bb + (barr + 1) * 64 + bj);
        f32x4 bNi = *(const f32x4*)(bb + (barr + 2) * 64 + bj);
        f32x4 bNh = *(const f32x4*)(bb + (barr + 3) * 64 + bj);
        const int ar = (mtj * 16 + L.col) * 64;
        f16x8 hR0 = *(const f16x8*)(lds + awh        + ar + L.x0);
        f16x8 hR1 = *(const f16x8*)(lds + awh        + ar + L.x1);
        f16x8 hZ0 = *(const f16x8*)(lds + awh + 4096 + ar + L.x0);
        f16x8 hZ1 = *(const f16x8*)(lds + awh + 4096 + ar + L.x1);
        f16x8 hN0 = *(const f16x8*)(lds + awh + 8192 + ar + L.x0);
        f16x8 hN1 = *(const f16x8*)(lds + awh + 8192 + ar + L.x1);
        f32x4 aR  = mfma16(hR0, hb0, bR);  aR  = mfma16(hR1, hb1, aR);
        f32x4 aZ  = mfma16(hZ0, hb0, bZ);  aZ  = mfma16(hZ1, hb1, aZ);
        f32x4 aNh = mfma16(hN0, hb0, bNh); aNh = mfma16(hN1, hb1, aNh);
        f32x4 aNi;
        if constexpr (PADX) {
            const int xp = (L.quad ^ (L.col & 3)) << 3;
            const int pr = (mtj * 16 + L.col) * 32;
            f16x8 pR = *(const f16x8*)(lds + WPADO        + pr + xp);
            f16x8 pZ = *(const f16x8*)(lds + WPADO + 2048 + pr + xp);
            f16x8 pN = *(const f16x8*)(lds + WPADO + 4096 + pr + xp);
            aR  = mfma16(pR, xpb, aR);
            aZ  = mfma16(pZ, xpb, aZ);
            aNi = mfma16(pN, xpb, bNi);
        } else {
            f16x8 xR0 = *(const f16x8*)(lds + awx        + ar + L.x0);
            f16x8 xR1 = *(const f16x8*)(lds + awx        + ar + L.x1);
            f16x8 xZ0 = *(const f16x8*)(lds + awx + 4096 + ar + L.x0);
            f16x8 xZ1 = *(const f16x8*)(lds + awx + 4096 + ar + L.x1);
            f16x8 xN0 = *(const f16x8*)(lds + awx + 8192 + ar + L.x0);
            f16x8 xN1 = *(const f16x8*)(lds + awx + 8192 + ar + L.x1);
            aR  = mfma16(xR0, xb0, aR);   aR  = mfma16(xR1, xb1, aR);
            aZ  = mfma16(xZ0, xb0, aZ);   aZ  = mfma16(xZ1, xb1, aZ);
            aNi = mfma16(xN0, xb0, bNi);  aNi = mfma16(xN1, xb1, aNi);
        }
        f16x4 o;
        #pragma unroll
        for (int i = 0; i < 4; ++i) {
            const float r = __builtin_amdgcn_rcpf(1.f + __builtin_amdgcn_exp2f(aR[i]));
            const float z = __builtin_amdgcn_rcpf(1.f + __builtin_amdgcn_exp2f(aZ[i]));
            const float n = 1.f - 2.f * __builtin_amdgcn_rcpf(1.f + __builtin_amdgcn_exp2f(aNi[i] + r * aNh[i]));
            const float h = n + z * ((float)ho[mtj][i] - n);
            o[i] = (f16)h;
        }
        ho[mtj] = o;
        *(f16x4*)(lds + hhoff + L.wo[mtj]) = o;
    }
}

__global__ __launch_bounds__(512, 2)
void gru_wave(
    const float* __restrict__ x,
    const float* __restrict__ eWih0, const float* __restrict__ eWhh0,
    const float* __restrict__ ebih0, const float* __restrict__ ebhh0,
    const float* __restrict__ eWih1, const float* __restrict__ eWhh1,
    const float* __restrict__ ebih1, const float* __restrict__ ebhh1,
    const float* __restrict__ dWih0, const float* __restrict__ dWhh0,
    const float* __restrict__ dbih0, const float* __restrict__ dbhh0,
    const float* __restrict__ dWih1, const float* __restrict__ dWhh1,
    const float* __restrict__ dbih1, const float* __restrict__ dbhh1,
    const float* __restrict__ fcW,  const float* __restrict__ fcb,
    float* __restrict__ out)
{
    extern __shared__ f16 lds[];
    float* bb = (float*)(lds + BIASH);
    const int tid  = threadIdx.x;
    const int lane = tid & 63;
    const int wv   = __builtin_amdgcn_readfirstlane(tid >> 6);

    Lane L;
    L.col  = lane & 15;
    L.quad = lane >> 4;
    L.c7   = L.col & 7;
    L.colr = L.col * 64;
    L.x0   = (L.quad ^ L.c7) << 3;
    L.x1   = ((4 + L.quad) ^ L.c7) << 3;
    #pragma unroll
    for (int mtj = 0; mtj < 4; ++mtj)
        L.wo[mtj] = L.colr + (((2 * mtj + (L.quad >> 1)) ^ L.c7) << 3) + ((L.quad & 1) << 2);

    const int r0    = blockIdx.x * 128;
    const int myrow = r0 + wv * 16 + L.col;
    const int h0off = HB + wv * 2048;
    const int h1off = h0off + 1024;

    // ---- encoder-phase staging ----
    stage_w(lds, W0H, eWhh0, tid);
    stage_w(lds, W1H, eWhh1, tid);
    stage_w(lds, W1X, eWih1, tid);
    stage_pad(lds, eWih0, tid);
    stage_bias(bb, 0, ebih0, ebhh0, tid);
    stage_bias(bb, 4, ebih1, ebhh1, tid);
    {   // zero this wave's h0+h1 (2048 halves)
        f16x8 z;
        #pragma unroll
        for (int i = 0; i < 8; ++i) z[i] = (f16)0.f;
        for (int k = lane; k < 256; k += 64) *(f16x8*)(lds + h0off + k * 8) = z;
    }
    f16x4 ho0[4], ho1[4];
    #pragma unroll
    for (int m = 0; m < 4; ++m) {
        #pragma unroll
        for (int i = 0; i < 4; ++i) { ho0[m][i] = (f16)0.f; ho1[m][i] = (f16)0.f; }
    }
    __syncthreads();

    const float* xrow = x + (size_t)myrow * (T_SEQ * 2);
    f16x8 zf;
    #pragma unroll
    for (int i = 0; i < 8; ++i) zf[i] = (f16)0.f;

    // ---- encoder: barrier-free ----
    #pragma unroll 1
    for (int t = 0; t < T_SEQ; ++t) {
        const float2 xv = *(const float2*)(xrow + t * 2);
        f16x8 xpb = zf;
        if (L.quad == 0) { xpb[0] = (f16)xv.x; xpb[1] = (f16)xv.y; }
        cell_<true >(lds, W0H, 0,   0,     h0off, 0, L, ho0, xpb);
        cell_<false>(lds, W1H, W1X, h0off, h1off, 4, L, ho1, zf);
    }

    // ---- phase switch (only barriers in the kernel) ----
    __syncthreads();
    stage_w(lds, W0H, dWhh0, tid);
    stage_w(lds, W1H, dWhh1, tid);
    stage_w(lds, W1X, dWih1, tid);
    stage_comp(lds, W0X, dWih0, fcW, tid);
    stage_pad(lds, dWih0, tid);
    stage_bias_fold(bb, 0, dbih0, dbhh0, dWih0, fcb, tid);
    stage_bias(bb, 4, dbih1, dbhh1, tid);
    stage_bias(bb, 8, dbih0, dbhh0, tid);
    __syncthreads();

    f16x8 fcf0 = zf, fcf1 = zf;
    if (L.col < 2) {
        #pragma unroll
        for (int i = 0; i < 8; ++i) {
            fcf0[i] = (f16)fcW[L.col * 64 + L.quad * 8 + i];
            fcf1[i] = (f16)fcW[L.col * 64 + 32 + L.quad * 8 + i];
        }
    }
    f32x4 pb;
    #pragma unroll
    for (int rg = 0; rg < 4; ++rg) pb[rg] = (L.quad == 0 && rg < 2) ? fcb[rg] : 0.f;

    float* __restrict__ outp = out + (size_t)myrow * (STEPS * 2);

    // ---- decoder step 0 (x-input = last x) ----
    {
        const float2 xv = *(const float2*)(xrow + (T_SEQ - 1) * 2);
        f16x8 xpb = zf;
        if (L.quad == 0) { xpb[0] = (f16)xv.x; xpb[1] = (f16)xv.y; }
        cell_<true >(lds, W0H, 0,   0,     h0off, 8, L, ho0, xpb);
        cell_<false>(lds, W1H, W1X, h0off, h1off, 4, L, ho1, zf);
        f16x8 b0 = *(const f16x8*)(lds + h1off + L.colr + L.x0);
        f16x8 b1 = *(const f16x8*)(lds + h1off + L.colr + L.x1);
        f32x4 p = mfma16(fcf0, b0, pb);
        p = mfma16(fcf1, b1, p);
        if (L.quad == 0) *(float2*)outp = make_float2(p[0], p[1]);
    }

    // ---- decoder steps 1..79: barrier-free, in-place h ----
    #pragma unroll 1
    for (int s = 1; s < STEPS; ++s) {
        cell_<false>(lds, W0H, W0X, h1off, h0off, 0, L, ho0, zf);
        cell_<false>(lds, W1H, W1X, h0off, h1off, 4, L, ho1, zf);
        f16x8 b0 = *(const f16x8*)(lds + h1off + L.colr + L.x0);
        f16x8 b1 = *(const f16x8*)(lds + h1off + L.colr + L.x1);
        f32x4 p = mfma16(fcf0, b0, pb);
        p = mfma16(fcf1, b1, p);
        if (L.quad == 0) *(float2*)(outp + s * 2) = make_float2(p[0], p[1]);
    }
}

extern "C" void kernel_launch(void* const* d_in, const int* in_sizes, int n_in,
                              void* d_out, int out_size, void* d_ws, size_t ws_size,
                              hipStream_t stream) {
    (void)n_in; (void)out_size; (void)d_ws; (void)ws_size;

    const float* x     = (const float*)d_in[0];
    const float* eWih0 = (const float*)d_in[1];
    const float* eWhh0 = (const float*)d_in[2];
    const float* ebih0 = (const float*)d_in[3];
    const float* ebhh0 = (const float*)d_in[4];
    const float* eWih1 = (const float*)d_in[5];
    const float* eWhh1 = (const float*)d_in[6];
    const float* ebih1 = (const float*)d_in[7];
    const float* ebhh1 = (const float*)d_in[8];
    const float* dWih0 = (const float*)d_in[9];
    const float* dWhh0 = (const float*)d_in[10];
    const float* dbih0 = (const float*)d_in[11];
    const float* dbhh0 = (const float*)d_in[12];
    const float* dWih1 = (const float*)d_in[13];
    const float* dWhh1 = (const float*)d_in[14];
    const float* dbih1 = (const float*)d_in[15];
    const float* dbhh1 = (const float*)d_in[16];
    const float* fcW   = (const float*)d_in[17];
    const float* fcb   = (const float*)d_in[18];
    float* out = (float*)d_out;

    // >64KB dynamic LDS requires the opt-in attribute (idempotent, host-side,
    // graph-capture safe: not a stream operation).
    static int attr_set = hipFuncSetAttribute((const void*)gru_wave,
        hipFuncAttributeMaxDynamicSharedMemorySize, LDS_BYTES);
    (void)attr_set;
    hipFuncSetAttribute((const void*)gru_wave,
        hipFuncAttributeMaxDynamicSharedMemorySize, LDS_BYTES);

    const int b = in_sizes[0] / (T_SEQ * 2);   // 32768
    dim3 grid(b / 128), block(512);
    hipLaunchKernelGGL(gru_wave, grid, block, LDS_BYTES, stream,
        x, eWih0, eWhh0, ebih0, ebhh0, eWih1, eWhh1, ebih1, ebhh1,
        dWih0, dWhh0, dbih0, dbhh0, dWih1, dWhh1, dbih1, dbhh1,
        fcW, fcb, out);
}

// Round 14
// 480.873 us; speedup vs baseline: 1.0588x; 1.0588x over previous
//
#include <hip/hip_runtime.h>
#include <cstddef>

#define T_SEQ 11
#define STEPS 80
#define SRC (-1.44269504f)
#define SNC ( 2.88539008f)

typedef _Float16 f16;
typedef _Float16 f16x4 __attribute__((ext_vector_type(4)));
typedef _Float16 f16x8 __attribute__((ext_vector_type(8)));
typedef float    f32x4 __attribute__((ext_vector_type(4)));

// ---- LDS layout (halves) ----------------------------------------------
// R13 BUG: WPADO is 192 rows x 32 halves = 6144 halves (12 KB), but HB was
// placed 3072 halves after it -> pN/pZ A-frag reads aliased live h-state.
#define W0H   0        // l0 Whh (192 x 64, swizzled)      12288 halves
#define W1X   12288    // l1 Wih                           12288 halves
#define WPADO 24576    // l0 x-side, 192 x 32 padded        6144 halves
#define HB    30720    // 8 waves x (h0:1024 + h1:1024)    16384 halves
#define BIASH 47104    // f32 region: 8 arrays x 64          512 floats
#define LDS_BYTES (47104*2 + 512*4)   // 96256 B

__device__ __forceinline__ f32x4 mfma16(f16x8 a, f16x8 b, f32x4 c) {
    return __builtin_amdgcn_mfma_f32_16x16x32_f16(a, b, c, 0, 0, 0);
}

// ---- staging -----------------------------------------------------------
__device__ __forceinline__ void stage_w(f16* lds, int dst, const float* __restrict__ W, int tid) {
    for (int c = tid; c < 1536; c += 512) {
        const int row = c >> 3, kc = c & 7;
        const float sc = (row < 128) ? SRC : SNC;
        const float* p = W + row * 64 + kc * 8;
        f16x8 v;
        #pragma unroll
        for (int i = 0; i < 8; ++i) v[i] = (f16)(sc * p[i]);
        *(f16x8*)(lds + dst + row * 64 + ((kc ^ (row & 7)) << 3)) = v;
    }
}
__device__ __forceinline__ void stage_pad(f16* lds, const float* __restrict__ Wih0, int tid) {
    for (int c = tid; c < 768; c += 512) {
        const int row = c >> 2, kc = c & 3;
        const float sc = (row < 128) ? SRC : SNC;
        f16x8 v;
        #pragma unroll
        for (int i = 0; i < 8; ++i) v[i] = (f16)0.f;
        if (kc == 0) { v[0] = (f16)(sc * Wih0[row * 2]); v[1] = (f16)(sc * Wih0[row * 2 + 1]); }
        *(f16x8*)(lds + WPADO + row * 32 + ((kc ^ (row & 3)) << 3)) = v;
    }
}
__device__ __forceinline__ void stage_bias(float* bb, int base, const float* __restrict__ bih,
                                           const float* __restrict__ bhh, int tid) {
    for (int t = tid; t < 256; t += 512) {
        const int a = t >> 6, j = t & 63;
        float v;
        if (a == 0)      v = SRC * (bih[j] + bhh[j]);
        else if (a == 1) v = SRC * (bih[64 + j] + bhh[64 + j]);
        else if (a == 2) v = SNC * bih[128 + j];
        else             v = SNC * bhh[128 + j];
        bb[(base + a) * 64 + j] = v;
    }
}

// A-frag from global: lane holds sc*W[row][k0..k0+7].
__device__ __forceinline__ f16x8 wfrag(const float* __restrict__ W, int row, int k0, float sc) {
    f16x8 r;
    #pragma unroll
    for (int i = 0; i < 8; ++i) r[i] = (f16)(sc * W[row * 64 + k0 + i]);
    return r;
}
// Register-cached Whh1 A-frags: [ks*4+mt], all 64 j (this wave owns all gates).
__device__ __forceinline__ void load_wregs(f16x8 (&R)[8], f16x8 (&Z)[8], f16x8 (&N)[8],
                                           const float* __restrict__ Whh, int col, int quad) {
    #pragma unroll
    for (int ks = 0; ks < 2; ++ks) {
        #pragma unroll
        for (int mt = 0; mt < 4; ++mt) {
            const int k0 = ks * 32 + quad * 8;
            R[ks * 4 + mt] = wfrag(Whh, mt * 16 + col,       k0, SRC);
            Z[ks * 4 + mt] = wfrag(Whh, 64  + mt * 16 + col, k0, SRC);
            N[ks * 4 + mt] = wfrag(Whh, 128 + mt * 16 + col, k0, SNC);
        }
    }
}

struct Lane {
    int col, quad, c7, colr, x0, x1, xp;
    int wo[4];
};

// l0 cell: x-side = single K=32 MFMA (WPADO, xpb B-frag built by caller),
// h-side from LDS W0H. In-place h0 update (wave-private, lgkmcnt-ordered).
__device__ __forceinline__ void cell_l0(f16* lds, const Lane& L, f16x4 (&ho)[4],
                                        f16x8 xpb, int h0off)
{
    const float* bb = (const float*)(lds + BIASH);
    f16x8 hb0 = *(const f16x8*)(lds + h0off + L.colr + L.x0);
    f16x8 hb1 = *(const f16x8*)(lds + h0off + L.colr + L.x1);
    #pragma unroll
    for (int mt = 0; mt < 4; ++mt) {
        const int bj = mt * 16 + L.quad * 4;
        f32x4 bR  = *(const f32x4*)(bb + 0 * 64 + bj);
        f32x4 bZ  = *(const f32x4*)(bb + 1 * 64 + bj);
        f32x4 bNi = *(const f32x4*)(bb + 2 * 64 + bj);
        f32x4 bNh = *(const f32x4*)(bb + 3 * 64 + bj);
        const int ar = (mt * 16 + L.col) * 64;
        f16x8 hR0 = *(const f16x8*)(lds + W0H        + ar + L.x0);
        f16x8 hR1 = *(const f16x8*)(lds + W0H        + ar + L.x1);
        f16x8 hZ0 = *(const f16x8*)(lds + W0H + 4096 + ar + L.x0);
        f16x8 hZ1 = *(const f16x8*)(lds + W0H + 4096 + ar + L.x1);
        f16x8 hN0 = *(const f16x8*)(lds + W0H + 8192 + ar + L.x0);
        f16x8 hN1 = *(const f16x8*)(lds + W0H + 8192 + ar + L.x1);
        const int pr = (mt * 16 + L.col) * 32;
        f16x8 pR = *(const f16x8*)(lds + WPADO        + pr + L.xp);
        f16x8 pZ = *(const f16x8*)(lds + WPADO + 2048 + pr + L.xp);
        f16x8 pN = *(const f16x8*)(lds + WPADO + 4096 + pr + L.xp);
        f32x4 aR  = mfma16(hR0, hb0, bR);  aR  = mfma16(hR1, hb1, aR);
        f32x4 aZ  = mfma16(hZ0, hb0, bZ);  aZ  = mfma16(hZ1, hb1, aZ);
        f32x4 aNh = mfma16(hN0, hb0, bNh); aNh = mfma16(hN1, hb1, aNh);
        aR  = mfma16(pR, xpb, aR);
        aZ  = mfma16(pZ, xpb, aZ);
        f32x4 aNi = mfma16(pN, xpb, bNi);
        f16x4 o;
        #pragma unroll
        for (int i = 0; i < 4; ++i) {
            const float r = __builtin_amdgcn_rcpf(1.f + __builtin_amdgcn_exp2f(aR[i]));
            const float z = __builtin_amdgcn_rcpf(1.f + __builtin_amdgcn_exp2f(aZ[i]));
            const float n = 1.f - 2.f * __builtin_amdgcn_rcpf(1.f + __builtin_amdgcn_exp2f(aNi[i] + r * aNh[i]));
            const float h = n + z * ((float)ho[mt][i] - n);
            o[i] = (f16)h;
        }
        ho[mt] = o;
        *(f16x4*)(lds + h0off + L.wo[mt]) = o;
    }
}

// l1 cell: x-side (h0) A-frags from LDS W1X; h-side (Whh1) from cached regs.
__device__ __forceinline__ void cell_l1(f16* lds, const Lane& L, f16x4 (&ho)[4],
    const f16x8 (&cR)[8], const f16x8 (&cZ)[8], const f16x8 (&cN)[8],
    int h0off, int h1off)
{
    const float* bb = (const float*)(lds + BIASH);
    f16x8 xb0 = *(const f16x8*)(lds + h0off + L.colr + L.x0);
    f16x8 xb1 = *(const f16x8*)(lds + h0off + L.colr + L.x1);
    f16x8 hb0 = *(const f16x8*)(lds + h1off + L.colr + L.x0);
    f16x8 hb1 = *(const f16x8*)(lds + h1off + L.colr + L.x1);
    #pragma unroll
    for (int mt = 0; mt < 4; ++mt) {
        const int bj = mt * 16 + L.quad * 4;
        f32x4 bR  = *(const f32x4*)(bb + 4 * 64 + bj);
        f32x4 bZ  = *(const f32x4*)(bb + 5 * 64 + bj);
        f32x4 bNi = *(const f32x4*)(bb + 6 * 64 + bj);
        f32x4 bNh = *(const f32x4*)(bb + 7 * 64 + bj);
        const int ar = (mt * 16 + L.col) * 64;
        f16x8 xR0 = *(const f16x8*)(lds + W1X        + ar + L.x0);
        f16x8 xR1 = *(const f16x8*)(lds + W1X        + ar + L.x1);
        f16x8 xZ0 = *(const f16x8*)(lds + W1X + 4096 + ar + L.x0);
        f16x8 xZ1 = *(const f16x8*)(lds + W1X + 4096 + ar + L.x1);
        f16x8 xN0 = *(const f16x8*)(lds + W1X + 8192 + ar + L.x0);
        f16x8 xN1 = *(const f16x8*)(lds + W1X + 8192 + ar + L.x1);
        f32x4 aR  = mfma16(cR[mt],     hb0, bR);
        f32x4 aZ  = mfma16(cZ[mt],     hb0, bZ);
        f32x4 aNh = mfma16(cN[mt],     hb0, bNh);
        aR  = mfma16(cR[4 + mt], hb1, aR);
        aZ  = mfma16(cZ[4 + mt], hb1, aZ);
        aNh = mfma16(cN[4 + mt], hb1, aNh);
        aR  = mfma16(xR0, xb0, aR);   aR  = mfma16(xR1, xb1, aR);
        aZ  = mfma16(xZ0, xb0, aZ);   aZ  = mfma16(xZ1, xb1, aZ);
        f32x4 aNi = mfma16(xN0, xb0, bNi); aNi = mfma16(xN1, xb1, aNi);
        f16x4 o;
        #pragma unroll
        for (int i = 0; i < 4; ++i) {
            const float r = __builtin_amdgcn_rcpf(1.f + __builtin_amdgcn_exp2f(aR[i]));
            const float z = __builtin_amdgcn_rcpf(1.f + __builtin_amdgcn_exp2f(aZ[i]));
            const float n = 1.f - 2.f * __builtin_amdgcn_rcpf(1.f + __builtin_amdgcn_exp2f(aNi[i] + r * aNh[i]));
            const float h = n + z * ((float)ho[mt][i] - n);
            o[i] = (f16)h;
        }
        ho[mt] = o;
        *(f16x4*)(lds + h1off + L.wo[mt]) = o;
    }
}

__global__ __launch_bounds__(512, 1)
void gru_wave3(
    const float* __restrict__ x,
    const float* __restrict__ eWih0, const float* __restrict__ eWhh0,
    const float* __restrict__ ebih0, const float* __restrict__ ebhh0,
    const float* __restrict__ eWih1, const float* __restrict__ eWhh1,
    const float* __restrict__ ebih1, const float* __restrict__ ebhh1,
    const float* __restrict__ dWih0, const float* __restrict__ dWhh0,
    const float* __restrict__ dbih0, const float* __restrict__ dbhh0,
    const float* __restrict__ dWih1, const float* __restrict__ dWhh1,
    const float* __restrict__ dbih1, const float* __restrict__ dbhh1,
    const float* __restrict__ fcW,  const float* __restrict__ fcb,
    float* __restrict__ out)
{
    extern __shared__ f16 lds[];
    float* bb = (float*)(lds + BIASH);
    const int tid  = threadIdx.x;
    const int lane = tid & 63;
    const int wv   = __builtin_amdgcn_readfirstlane(tid >> 6);

    Lane L;
    L.col  = lane & 15;
    L.quad = lane >> 4;
    L.c7   = L.col & 7;
    L.colr = L.col * 64;
    L.x0   = (L.quad ^ L.c7) << 3;
    L.x1   = ((4 + L.quad) ^ L.c7) << 3;
    L.xp   = (L.quad ^ (L.col & 3)) << 3;
    #pragma unroll
    for (int mt = 0; mt < 4; ++mt)
        L.wo[mt] = L.colr + (((2 * mt + (L.quad >> 1)) ^ L.c7) << 3) + ((L.quad & 1) << 2);

    const int r0    = blockIdx.x * 128;
    const int myrow = r0 + wv * 16 + L.col;
    const int h0off = HB + wv * 2048;
    const int h1off = h0off + 1024;

    // ---- encoder-phase staging ----
    stage_w(lds, W0H, eWhh0, tid);
    stage_w(lds, W1X, eWih1, tid);
    stage_pad(lds, eWih0, tid);
    stage_bias(bb, 0, ebih0, ebhh0, tid);
    stage_bias(bb, 4, ebih1, ebhh1, tid);
    {
        f16x8 z;
        #pragma unroll
        for (int i = 0; i < 8; ++i) z[i] = (f16)0.f;
        for (int k = lane; k < 256; k += 64) *(f16x8*)(lds + h0off + k * 8) = z;
    }
    f16x8 w1R[8], w1Z[8], w1N[8];
    load_wregs(w1R, w1Z, w1N, eWhh1, L.col, L.quad);
    f16x4 ho0[4], ho1[4];
    #pragma unroll
    for (int m = 0; m < 4; ++m) {
        #pragma unroll
        for (int i = 0; i < 4; ++i) { ho0[m][i] = (f16)0.f; ho1[m][i] = (f16)0.f; }
    }
    __syncthreads();

    const float* xrow = x + (size_t)myrow * (T_SEQ * 2);
    f16x8 zf;
    #pragma unroll
    for (int i = 0; i < 8; ++i) zf[i] = (f16)0.f;

    // ---- encoder: barrier-free ----
    #pragma unroll 1
    for (int t = 0; t < T_SEQ; ++t) {
        const float2 xv = *(const float2*)(xrow + t * 2);
        f16x8 xpb = zf;
        if (L.quad == 0) { xpb[0] = (f16)xv.x; xpb[1] = (f16)xv.y; }
        cell_l0(lds, L, ho0, xpb, h0off);
        cell_l1(lds, L, ho1, w1R, w1Z, w1N, h0off, h1off);
    }

    // ---- phase switch (only barriers in the kernel) ----
    __syncthreads();
    stage_w(lds, W0H, dWhh0, tid);
    stage_w(lds, W1X, dWih1, tid);
    stage_pad(lds, dWih0, tid);
    stage_bias(bb, 0, dbih0, dbhh0, tid);
    stage_bias(bb, 4, dbih1, dbhh1, tid);
    load_wregs(w1R, w1Z, w1N, dWhh1, L.col, L.quad);
    __syncthreads();

    f16x8 fcf0 = zf, fcf1 = zf;
    if (L.col < 2) {
        #pragma unroll
        for (int i = 0; i < 8; ++i) {
            fcf0[i] = (f16)fcW[L.col * 64 + L.quad * 8 + i];
            fcf1[i] = (f16)fcW[L.col * 64 + 32 + L.quad * 8 + i];
        }
    }
    f32x4 pb;
    #pragma unroll
    for (int rg = 0; rg < 4; ++rg) pb[rg] = (L.quad == 0 && rg < 2) ? fcb[rg] : 0.f;

    float* __restrict__ outp = out + (size_t)myrow * (STEPS * 2);

    // decoder step-0 x-input: last encoder x (same lanes/positions as pred).
    f16x8 xpb = zf;
    {
        const float2 xv = *(const float2*)(xrow + (T_SEQ - 1) * 2);
        if (L.quad == 0) { xpb[0] = (f16)xv.x; xpb[1] = (f16)xv.y; }
    }

    // ---- decoder: uniform, barrier-free; pred feeds back in-lane ----
    #pragma unroll 1
    for (int s = 0; s < STEPS; ++s) {
        cell_l0(lds, L, ho0, xpb, h0off);
        cell_l1(lds, L, ho1, w1R, w1Z, w1N, h0off, h1off);
        f16x8 b0 = *(const f16x8*)(lds + h1off + L.colr + L.x0);
        f16x8 b1 = *(const f16x8*)(lds + h1off + L.colr + L.x1);
        f32x4 p = mfma16(fcf0, b0, pb);
        p = mfma16(fcf1, b1, p);
        // FC D layout: (m=quad*4+rg, n=col) -> pred0/pred1 live in quad==0
        // lanes at p[0],p[1] == exactly the K=32 B-frag slots for next l0.
        xpb = zf;
        if (L.quad == 0) {
            *(float2*)(outp + s * 2) = make_float2(p[0], p[1]);
            xpb[0] = (f16)p[0];
            xpb[1] = (f16)p[1];
        }
    }
}

extern "C" void kernel_launch(void* const* d_in, const int* in_sizes, int n_in,
                              void* d_out, int out_size, void* d_ws, size_t ws_size,
                              hipStream_t stream) {
    (void)n_in; (void)out_size; (void)d_ws; (void)ws_size;

    const float* x     = (const float*)d_in[0];
    const float* eWih0 = (const float*)d_in[1];
    const float* eWhh0 = (const float*)d_in[2];
    const float* ebih0 = (const float*)d_in[3];
    const float* ebhh0 = (const float*)d_in[4];
    const float* eWih1 = (const float*)d_in[5];
    const float* eWhh1 = (const float*)d_in[6];
    const float* ebih1 = (const float*)d_in[7];
    const float* ebhh1 = (const float*)d_in[8];
    const float* dWih0 = (const float*)d_in[9];
    const float* dWhh0 = (const float*)d_in[10];
    const float* dbih0 = (const float*)d_in[11];
    const float* dbhh0 = (const float*)d_in[12];
    const float* dWih1 = (const float*)d_in[13];
    const float* dWhh1 = (const float*)d_in[14];
    const float* dbih1 = (const float*)d_in[15];
    const float* dbhh1 = (const float*)d_in[16];
    const float* fcW   = (const float*)d_in[17];
    const float* fcb   = (const float*)d_in[18];
    float* out = (float*)d_out;

    hipFuncSetAttribute((const void*)gru_wave3,
        hipFuncAttributeMaxDynamicSharedMemorySize, LDS_BYTES);

    const int b = in_sizes[0] / (T_SEQ * 2);   // 32768
    dim3 grid(b / 128), block(512);
    hipLaunchKernelGGL(gru_wave3, grid, block, LDS_BYTES, stream,
        x, eWih0, eWhh0, ebih0, ebhh0, eWih1, eWhh1, ebih1, ebhh1,
        dWih0, dWhh0, dbih0, dbhh0, dWih1, dWhh1, dbih1, dbhh1,
        fcW, fcb, out);
}